// Round 1
// baseline (1137.792 us; speedup 1.0000x reference)
//
#include <hip/hip_runtime.h>

#define NLEV 20
#define TSIZE (1u << 19)
#define TMASK (TSIZE - 1u)
#define PRIME_Y 2654435761u
#define PRIME_Z 805459861u

// int(16 * 1.39**i) for i in 0..19 (Python float pow, truncated) — verified,
// none within 0.02 of an integer boundary so double-ulp drift can't flip them.
__device__ __constant__ int kRes[NLEV] = {
    16, 22, 30, 42, 59, 83, 115, 160, 222, 309,
    430, 598, 832, 1156, 1608, 2235, 3107, 4318, 6003, 8344};

__global__ __launch_bounds__(256) void hash_enc_kernel(
    const float* __restrict__ x, const float* __restrict__ tables,
    float* __restrict__ out, int n) {
  int p = blockIdx.x * 256 + threadIdx.x;
  if (p >= n) return;

  const float px = x[3 * p + 0];
  const float py = x[3 * p + 1];
  const float pz = x[3 * p + 2];

  float o[NLEV * 2];

#pragma unroll
  for (int l = 0; l < NLEV; ++l) {
    const float r = (float)kRes[l];
    const float xs0 = px * r, xs1 = py * r, xs2 = pz * r;
    const float f0 = floorf(xs0), f1 = floorf(xs1), f2 = floorf(xs2);
    const float wx = xs0 - f0, wy = xs1 - f1, wz = xs2 - f2;
    const unsigned v0 = (unsigned)(int)f0;
    const unsigned v1 = (unsigned)(int)f1;
    const unsigned v2 = (unsigned)(int)f2;

    // h = cx ^ (cy * PRIME_Y) ^ (cz * PRIME_Z), idx = h & (T-1)
    const unsigned hx0 = v0;
    const unsigned hx1 = v0 + 1u;
    const unsigned hy0 = v1 * PRIME_Y;
    const unsigned hy1 = (v1 + 1u) * PRIME_Y;
    const unsigned hz0 = v2 * PRIME_Z;
    const unsigned hz1 = (v2 + 1u) * PRIME_Z;

    const float2* __restrict__ tbl =
        (const float2*)tables + (size_t)l * TSIZE;

    // Corner n = (i,j,k) with i=n>>2, j=(n>>1)&1, k=n&1  (OFFSETS order)
    const float2 e000 = tbl[(hx0 ^ hy0 ^ hz0) & TMASK];  // e[:,0]
    const float2 e001 = tbl[(hx0 ^ hy0 ^ hz1) & TMASK];  // e[:,1]
    const float2 e010 = tbl[(hx0 ^ hy1 ^ hz0) & TMASK];  // e[:,2]
    const float2 e011 = tbl[(hx0 ^ hy1 ^ hz1) & TMASK];  // e[:,3]
    const float2 e100 = tbl[(hx1 ^ hy0 ^ hz0) & TMASK];  // e[:,4]
    const float2 e101 = tbl[(hx1 ^ hy0 ^ hz1) & TMASK];  // e[:,5]
    const float2 e110 = tbl[(hx1 ^ hy1 ^ hz0) & TMASK];  // e[:,6]
    const float2 e111 = tbl[(hx1 ^ hy1 ^ hz1) & TMASK];  // e[:,7]

    const float owx = 1.0f - wx, owy = 1.0f - wy, owz = 1.0f - wz;

    // channel 0
    const float c00a = e000.x * owx + e100.x * wx;
    const float c01a = e001.x * owx + e101.x * wx;
    const float c10a = e010.x * owx + e110.x * wx;
    const float c11a = e011.x * owx + e111.x * wx;
    const float c0a = c00a * owy + c10a * wy;
    const float c1a = c01a * owy + c11a * wy;
    o[2 * l + 0] = c0a * owz + c1a * wz;
    // channel 1
    const float c00b = e000.y * owx + e100.y * wx;
    const float c01b = e001.y * owx + e101.y * wx;
    const float c10b = e010.y * owx + e110.y * wx;
    const float c11b = e011.y * owx + e111.y * wx;
    const float c0b = c00b * owy + c10b * wy;
    const float c1b = c01b * owy + c11b * wy;
    o[2 * l + 1] = c0b * owz + c1b * wz;
  }

  // Row is 40 floats = 160 B, 16 B aligned -> 10 float4 stores.
  float4* __restrict__ dst = (float4*)(out + (size_t)p * (NLEV * 2));
#pragma unroll
  for (int k = 0; k < 10; ++k) {
    dst[k] = make_float4(o[4 * k + 0], o[4 * k + 1], o[4 * k + 2], o[4 * k + 3]);
  }
}

extern "C" void kernel_launch(void* const* d_in, const int* in_sizes, int n_in,
                              void* d_out, int out_size, void* d_ws, size_t ws_size,
                              hipStream_t stream) {
  const float* x = (const float*)d_in[0];       // (N, 3) f32
  const float* tables = (const float*)d_in[1];  // (20, 2^19, 2) f32
  float* out = (float*)d_out;                   // (N, 40) f32
  const int n = in_sizes[0] / 3;
  const int grid = (n + 255) / 256;
  hash_enc_kernel<<<grid, 256, 0, stream>>>(x, tables, out, n);
}

// Round 2
// 771.831 us; speedup vs baseline: 1.4741x; 1.4741x over previous
//
#include <hip/hip_runtime.h>

#define NLEV 20
#define TSIZE (1u << 19)
#define TMASK (TSIZE - 1u)
#define PRIME_Y 2654435761u
#define PRIME_Z 805459861u

// int(16 * 1.39**i) for i in 0..19 — verified, none near an integer boundary.
__device__ __constant__ int kRes[NLEV] = {
    16, 22, 30, 42, 59, 83, 115, 160, 222, 309,
    430, 598, 832, 1156, 1608, 2235, 3107, 4318, 6003, 8344};

__device__ __forceinline__ float2 encode_one(const float* __restrict__ tables,
                                             int l, float px, float py, float pz) {
  const float r = (float)kRes[l];
  const float xs0 = px * r, xs1 = py * r, xs2 = pz * r;
  const float f0 = floorf(xs0), f1 = floorf(xs1), f2 = floorf(xs2);
  const float wx = xs0 - f0, wy = xs1 - f1, wz = xs2 - f2;
  const unsigned v0 = (unsigned)(int)f0;
  const unsigned v1 = (unsigned)(int)f1;
  const unsigned v2 = (unsigned)(int)f2;

  const unsigned hx0 = v0, hx1 = v0 + 1u;
  const unsigned hy0 = v1 * PRIME_Y, hy1 = (v1 + 1u) * PRIME_Y;
  const unsigned hz0 = v2 * PRIME_Z, hz1 = (v2 + 1u) * PRIME_Z;

  const float2* __restrict__ tbl = (const float2*)tables + (size_t)l * TSIZE;

  const float2 e000 = tbl[(hx0 ^ hy0 ^ hz0) & TMASK];
  const float2 e001 = tbl[(hx0 ^ hy0 ^ hz1) & TMASK];
  const float2 e010 = tbl[(hx0 ^ hy1 ^ hz0) & TMASK];
  const float2 e011 = tbl[(hx0 ^ hy1 ^ hz1) & TMASK];
  const float2 e100 = tbl[(hx1 ^ hy0 ^ hz0) & TMASK];
  const float2 e101 = tbl[(hx1 ^ hy0 ^ hz1) & TMASK];
  const float2 e110 = tbl[(hx1 ^ hy1 ^ hz0) & TMASK];
  const float2 e111 = tbl[(hx1 ^ hy1 ^ hz1) & TMASK];

  const float owx = 1.0f - wx, owy = 1.0f - wy, owz = 1.0f - wz;

  const float c00a = e000.x * owx + e100.x * wx;
  const float c01a = e001.x * owx + e101.x * wx;
  const float c10a = e010.x * owx + e110.x * wx;
  const float c11a = e011.x * owx + e111.x * wx;
  const float c0a = c00a * owy + c10a * wy;
  const float c1a = c01a * owy + c11a * wy;

  const float c00b = e000.y * owx + e100.y * wx;
  const float c01b = e001.y * owx + e101.y * wx;
  const float c10b = e010.y * owx + e110.y * wx;
  const float c11b = e011.y * owx + e111.y * wx;
  const float c0b = c00b * owy + c10b * wy;
  const float c1b = c01b * owy + c11b * wy;

  return make_float2(c0a * owz + c1a * wz, c0b * owz + c1b * wz);
}

// Kernel 1: one (point, level) per thread, level-major dispatch (blockIdx.y =
// level, dispatched after all lower levels' blocks) so each XCD's 4 MB L2
// holds ~one level's 4 MB table at a time. Writes level-major to ws:
// ws[(l*n + p)] as float2 — fully coalesced 2 KB/wave stores.
__global__ __launch_bounds__(256) void enc_level_kernel(
    const float* __restrict__ x, const float* __restrict__ tables,
    float2* __restrict__ ws, int n) {
  const int l = blockIdx.y;
  const int p = blockIdx.x * 256 + threadIdx.x;
  if (p >= n) return;
  const float px = x[3 * p + 0];
  const float py = x[3 * p + 1];
  const float pz = x[3 * p + 2];
  ws[(size_t)l * n + p] = encode_one(tables, l, px, py, pz);
}

// Kernel 2: transpose ws (20, N, 2) -> out (N, 40) via LDS tile of 256 points.
// LDS row stride 41 floats (odd) to avoid bank conflicts on both phases.
__global__ __launch_bounds__(256) void transpose_kernel(
    const float2* __restrict__ ws, float* __restrict__ out, int n) {
  __shared__ float lds[256 * 41];
  const int p0 = blockIdx.x * 256;
  const int t = threadIdx.x;
  const int npts = min(256, n - p0);

#pragma unroll
  for (int l = 0; l < NLEV; ++l) {
    if (t < npts) {
      const float2 v = ws[(size_t)l * n + p0 + t];
      lds[t * 41 + 2 * l + 0] = v.x;
      lds[t * 41 + 2 * l + 1] = v.y;
    }
  }
  __syncthreads();

  const int total4 = npts * 10;  // float4s this block must write
  float4* __restrict__ dst = (float4*)(out + (size_t)p0 * (NLEV * 2));
#pragma unroll
  for (int k = 0; k < 10; ++k) {
    const int g = t + k * 256;
    if (g < total4) {
      const int pl = g / 10;          // local point
      const int comp = g - pl * 10;   // float4 index within row
      const float* s = &lds[pl * 41 + comp * 4];
      dst[g] = make_float4(s[0], s[1], s[2], s[3]);
    }
  }
}

// Fallback (R1 kernel): direct per-point, all levels, used only if ws too small.
__global__ __launch_bounds__(256) void hash_enc_kernel(
    const float* __restrict__ x, const float* __restrict__ tables,
    float* __restrict__ out, int n) {
  int p = blockIdx.x * 256 + threadIdx.x;
  if (p >= n) return;
  const float px = x[3 * p + 0];
  const float py = x[3 * p + 1];
  const float pz = x[3 * p + 2];
  float o[NLEV * 2];
#pragma unroll
  for (int l = 0; l < NLEV; ++l) {
    const float2 v = encode_one(tables, l, px, py, pz);
    o[2 * l + 0] = v.x;
    o[2 * l + 1] = v.y;
  }
  float4* __restrict__ dst = (float4*)(out + (size_t)p * (NLEV * 2));
#pragma unroll
  for (int k = 0; k < 10; ++k) {
    dst[k] = make_float4(o[4 * k + 0], o[4 * k + 1], o[4 * k + 2], o[4 * k + 3]);
  }
}

extern "C" void kernel_launch(void* const* d_in, const int* in_sizes, int n_in,
                              void* d_out, int out_size, void* d_ws, size_t ws_size,
                              hipStream_t stream) {
  const float* x = (const float*)d_in[0];       // (N, 3) f32
  const float* tables = (const float*)d_in[1];  // (20, 2^19, 2) f32
  float* out = (float*)d_out;                   // (N, 40) f32
  const int n = in_sizes[0] / 3;
  const size_t ws_needed = (size_t)NLEV * n * 2 * sizeof(float);

  if (ws_size >= ws_needed) {
    const int pblocks = (n + 255) / 256;
    dim3 grid1(pblocks, NLEV);
    enc_level_kernel<<<grid1, 256, 0, stream>>>(x, tables, (float2*)d_ws, n);
    transpose_kernel<<<pblocks, 256, 0, stream>>>((const float2*)d_ws, out, n);
  } else {
    const int grid = (n + 255) / 256;
    hash_enc_kernel<<<grid, 256, 0, stream>>>(x, tables, out, n);
  }
}